// Round 1
// baseline (2509.276 us; speedup 1.0000x reference)
//
#include <hip/hip_runtime.h>

#define B_ 32
#define T_ 120
#define E_ 256
#define H_ 512
#define NSPAN 36960   // B_ * 1155

typedef __attribute__((ext_vector_type(8))) short short8;
typedef __attribute__((ext_vector_type(4))) float f32x4;

__device__ __forceinline__ short f2bf(float x) {
    union { float f; unsigned u; } v; v.f = x;
    unsigned r = v.u + 0x7fffu + ((v.u >> 16) & 1u);
    return (short)(r >> 16);
}
__device__ __forceinline__ float bf2f(unsigned short x) {
    union { unsigned u; float f; } v; v.u = ((unsigned)x) << 16;
    return v.f;
}

// ---------------- gather tokens -> x bf16 (row m = t*32 + b) ----------------
__global__ void k_gather(const int* __restrict__ tokens, const float* __restrict__ emb,
                         short* __restrict__ xbf) {
    int m = blockIdx.x;              // 0..3839, m = t*32+b
    int t = m >> 5, b = m & 31;
    int tok = tokens[b * T_ + t];
    int e = threadIdx.x;             // 256
    xbf[(size_t)m * E_ + e] = f2bf(emb[(size_t)tok * E_ + e]);
}

// ---------------- fp32 -> bf16 convert ----------------
__global__ void k_convert(const float* __restrict__ src, short* __restrict__ dst, int n8) {
    int i = blockIdx.x * blockDim.x + threadIdx.x;
    if (i >= n8) return;
    const float4* s4 = (const float4*)src + (size_t)i * 2;
    float4 a = s4[0], b = s4[1];
    short8 o;
    o[0]=f2bf(a.x); o[1]=f2bf(a.y); o[2]=f2bf(a.z); o[3]=f2bf(a.w);
    o[4]=f2bf(b.x); o[5]=f2bf(b.y); o[6]=f2bf(b.z); o[7]=f2bf(b.w);
    *(short8*)(dst + (size_t)i * 8) = o;
}

__global__ void k_biascomb(const float* __restrict__ bf1, const float* __restrict__ bf2,
                           const float* __restrict__ bb1, const float* __restrict__ bb2,
                           float* __restrict__ out) {
    int i = blockIdx.x * 256 + threadIdx.x;   // 4096
    out[i] = (i < 2048) ? (bf1[i] + bf2[i]) : (bb1[i - 2048] + bb2[i - 2048]);
}

// ---------------- generic bf16 MFMA GEMM: out = A(MxK) @ W(NxK)^T + bias ----------------
// EPI 0: fp32 row-major out ; EPI 1: relu -> bf16 row-major ; EPI 2: bf16 scatter to xg[t][n][b]
template <int EPI>
__global__ void __launch_bounds__(256) k_gemm(const short* __restrict__ A,
                                              const short* __restrict__ W,
                                              const float* __restrict__ bias,
                                              float* __restrict__ outF,
                                              short* __restrict__ outB,
                                              int N, int K) {
    int w = threadIdx.x >> 6, l = threadIdx.x & 63;
    int la = l & 15, lb = l >> 4;
    int m0 = blockIdx.x * 64 + w * 16;
    int nb = blockIdx.y * 64;
    const short* Ap = A + (size_t)(m0 + la) * K + lb * 8;
    const short* Wp = W + (size_t)(nb + la) * K + lb * 8;
    f32x4 acc0 = {0.f,0.f,0.f,0.f}, acc1 = acc0, acc2 = acc0, acc3 = acc0;
    for (int k0 = 0; k0 < K; k0 += 32) {
        short8 a  = *(const short8*)(Ap + k0);
        short8 b0 = *(const short8*)(Wp + k0);
        short8 b1 = *(const short8*)(Wp + (size_t)16 * K + k0);
        short8 b2 = *(const short8*)(Wp + (size_t)32 * K + k0);
        short8 b3 = *(const short8*)(Wp + (size_t)48 * K + k0);
        acc0 = __builtin_amdgcn_mfma_f32_16x16x32_bf16(a, b0, acc0, 0, 0, 0);
        acc1 = __builtin_amdgcn_mfma_f32_16x16x32_bf16(a, b1, acc1, 0, 0, 0);
        acc2 = __builtin_amdgcn_mfma_f32_16x16x32_bf16(a, b2, acc2, 0, 0, 0);
        acc3 = __builtin_amdgcn_mfma_f32_16x16x32_bf16(a, b3, acc3, 0, 0, 0);
    }
    f32x4 accs[4] = {acc0, acc1, acc2, acc3};
    #pragma unroll
    for (int j = 0; j < 4; ++j) {
        int n = nb + j * 16 + la;
        float bv = bias[n];
        #pragma unroll
        for (int r = 0; r < 4; ++r) {
            int m = m0 + lb * 4 + r;
            float v = accs[j][r] + bv;
            if (EPI == 0) {
                outF[(size_t)m * N + n] = v;
            } else if (EPI == 1) {
                outB[(size_t)m * N + n] = f2bf(fmaxf(v, 0.f));
            } else {
                int t = m >> 5, b = m & 31;
                outB[(((size_t)t * 4096 + n) << 5) + b] = f2bf(v);
            }
        }
    }
}

// ---------------- persistent bidirectional LSTM ----------------
// 64 blocks: dir = bid>>5, jslice = bid&31 (16 j's). Wave w owns 4 j's (jw..jw+3),
// gate rows rr = gate*4+jj in LDS (XOR-swizzled). Per step: MFMA (32x64x512),
// in-wave gate combine via shfl_xor, c in registers, h broadcast via global + ctr barrier.
__global__ void __launch_bounds__(256, 1) k_lstm(const short* __restrict__ xg,
                                                 const short* __restrict__ whh,
                                                 short* __restrict__ hbuf,
                                                 short* __restrict__ rnn,
                                                 int* __restrict__ ctr) {
    __shared__ short wlds[4][16][512];   // 64 KiB
    int w = threadIdx.x >> 6, l = threadIdx.x & 63;
    int la = l & 15, lb = l >> 4;
    int bid = blockIdx.x;
    int dir = bid >> 5, jsl = bid & 31;
    int jw = jsl * 16 + w * 4;

    // stage weights, swizzled: row rr at byte rr*1024, 16B chunk c16 at (c16*16)^((rr&7)<<4)
    {
        char* base = (char*)&wlds[w][0][0];
        for (int cc = l; cc < 1024; cc += 64) {
            int rr = cc >> 6, c16 = cc & 63;
            int gate = rr >> 2, jj = rr & 3;
            short8 v = *(const short8*)(whh + ((size_t)dir * 2048 + gate * 512 + jw + jj) * 512 + c16 * 8);
            *(short8*)(base + rr * 1024 + ((c16 * 16) ^ ((rr & 7) << 4))) = v;
        }
    }
    __syncthreads();

    float cst[2][4] = {{0.f,0.f,0.f,0.f},{0.f,0.f,0.f,0.f}};
    int gate = la >> 2;
    int grow = dir * 2048 + gate * 512 + jw + (la & 3);
    const char* wbase = (const char*)&wlds[w][0][0];
    int swz = (la & 7) << 4;
    int rowoff = la * 1024;

    for (int s = 0; s < T_; ++s) {
        int t = dir ? (T_ - 1 - s) : s;
        int cur = s & 1;
        const short* hb = hbuf + (size_t)(dir * 2 + cur) * (32 * 512);
        short* hn = hbuf + (size_t)(dir * 2 + (1 - cur)) * (32 * 512);

        // xg gather (early issue)
        const short* xgp = xg + ((size_t)t * 4096 + grow) * 32;
        float xv[2][4];
        #pragma unroll
        for (int mt = 0; mt < 2; ++mt)
            #pragma unroll
            for (int r = 0; r < 4; ++r)
                xv[mt][r] = bf2f((unsigned short)xgp[mt * 16 + lb * 4 + r]);

        f32x4 a0 = {0.f,0.f,0.f,0.f}, a1 = {0.f,0.f,0.f,0.f};
        #pragma unroll 4
        for (int ks = 0; ks < 16; ++ks) {
            short8 bfr = *(const short8*)(wbase + rowoff + ((ks * 64 + lb * 16) ^ swz));
            short8 h0 = *(const short8*)(hb + (size_t)la * 512 + ks * 32 + lb * 8);
            short8 h1 = *(const short8*)(hb + (size_t)(16 + la) * 512 + ks * 32 + lb * 8);
            a0 = __builtin_amdgcn_mfma_f32_16x16x32_bf16(h0, bfr, a0, 0, 0, 0);
            a1 = __builtin_amdgcn_mfma_f32_16x16x32_bf16(h1, bfr, a1, 0, 0, 0);
        }

        float val[2][4];
        #pragma unroll
        for (int mt = 0; mt < 2; ++mt) {
            #pragma unroll
            for (int r = 0; r < 4; ++r) {
                float x = (mt ? a1[r] : a0[r]) + xv[mt][r];
                val[mt][r] = (gate == 2) ? tanhf(x) : (1.f / (1.f + expf(-x)));
            }
        }

        #pragma unroll
        for (int mt = 0; mt < 2; ++mt) {
            #pragma unroll
            for (int r = 0; r < 4; ++r) {
                float v = val[mt][r];
                float vf = __shfl_xor(v, 4);
                float vg = __shfl_xor(v, 8);
                float vo = __shfl_xor(v, 12);
                if (la < 4) {   // gate==0 lanes: v=sig(i), vf=sig(f), vg=tanh(g), vo=sig(o)
                    float c = vf * cst[mt][r] + v * vg;
                    cst[mt][r] = c;
                    float h = vo * tanhf(c);
                    short hv = f2bf(h);
                    int b = mt * 16 + lb * 4 + r;
                    hn[(size_t)b * 512 + jw + la] = hv;
                    rnn[((size_t)b * T_ + t) * 1024 + dir * 512 + jw + la] = hv;
                }
            }
        }

        // device-scope barrier among this direction's 128 waves
        int* cp = ctr + dir * T_ + s;
        __builtin_amdgcn_fence(__ATOMIC_RELEASE, "agent");
        if (l == 0) __hip_atomic_fetch_add(cp, 1, __ATOMIC_RELAXED, __HIP_MEMORY_SCOPE_AGENT);
        while (__hip_atomic_load(cp, __ATOMIC_RELAXED, __HIP_MEMORY_SCOPE_AGENT) < 128)
            __builtin_amdgcn_s_sleep(1);
        __builtin_amdgcn_fence(__ATOMIC_ACQUIRE, "agent");
    }
}

// ---------------- LayerNorm (wave per row of 512) ----------------
__global__ void k_ln(const float* __restrict__ h2, const float* __restrict__ gam,
                     const float* __restrict__ bet, float* __restrict__ tr) {
    int w = threadIdx.x >> 6, l = threadIdx.x & 63;
    size_t row = (size_t)blockIdx.x * 4 + w;
    const float* x = h2 + row * 512;
    float v[8], s = 0.f, s2 = 0.f;
    #pragma unroll
    for (int i = 0; i < 8; ++i) { v[i] = x[l + 64 * i]; s += v[i]; s2 += v[i] * v[i]; }
    #pragma unroll
    for (int off = 32; off; off >>= 1) { s += __shfl_xor(s, off); s2 += __shfl_xor(s2, off); }
    float mu = s * (1.f / 512.f);
    float var = s2 * (1.f / 512.f) - mu * mu;
    float rstd = 1.f / sqrtf(var + 1e-5f);
    float* o = tr + row * 512;
    #pragma unroll
    for (int i = 0; i < 8; ++i) { int k = l + 64 * i; o[k] = (v[i] - mu) * rstd * gam[k] + bet[k]; }
}

// ---------------- cumsum over t (block per batch, thread per feature) ----------------
__global__ void k_cumsum(const float* __restrict__ tr, float* __restrict__ cs) {
    int b = blockIdx.x, f = threadIdx.x;  // 512 threads
    cs[((size_t)b * 121) * 512 + f] = 0.f;
    const float* src = tr + ((size_t)b * 120) * 512 + f;
    float* dst = cs + ((size_t)b * 121 + 1) * 512 + f;
    float run = 0.f;
    float nxt = src[0];
    for (int t = 0; t < 120; ++t) {
        float c = nxt;
        if (t < 119) nxt = src[(size_t)(t + 1) * 512];
        run += c;
        dst[(size_t)t * 512] = run;
    }
}

// ---------------- spans + label GEMM (wave per span) ----------------
__global__ void __launch_bounds__(256) k_span(const float* __restrict__ cs,
                                              const float* __restrict__ lw,
                                              const float* __restrict__ lbias,
                                              float* __restrict__ out) {
    __shared__ float wl[20][512];
    for (int idx = threadIdx.x; idx < 20 * 512; idx += 256) {
        int c = idx >> 9, k = idx & 511;
        wl[c][k] = lw[(size_t)k * 20 + c];
    }
    __syncthreads();
    int w = threadIdx.x >> 6, l = threadIdx.x & 63;
    int nw = gridDim.x * 4;
    for (int sp = blockIdx.x * 4 + w; sp < NSPAN; sp += nw) {
        int b = sp / 1155, s = sp - b * 1155;
        int beg, len;
        if (s < 1110) { beg = s / 10; len = s - beg * 10 + 1; }
        else {
            int t2 = s - 1110; beg = 111; int ll = 9;
            while (t2 >= ll) { t2 -= ll; --ll; ++beg; }
            len = t2 + 1;
        }
        int end = beg + len;
        const float* ce = cs + ((size_t)b * 121 + end) * 512;
        const float* cb = cs + ((size_t)b * 121 + beg) * 512;
        float inv = 1.f / (float)len;
        float p[20];
        #pragma unroll
        for (int c = 0; c < 20; ++c) p[c] = 0.f;
        #pragma unroll
        for (int i = 0; i < 8; ++i) {
            int k = l + 64 * i;
            float d = (ce[k] - cb[k]) * inv;
            #pragma unroll
            for (int c = 0; c < 20; ++c) p[c] += d * wl[c][k];
        }
        #pragma unroll
        for (int off = 32; off; off >>= 1) {
            #pragma unroll
            for (int c = 0; c < 20; ++c) p[c] += __shfl_xor(p[c], off);
        }
        if (l == 0) {
            float* o = out + (size_t)sp * 20;
            #pragma unroll
            for (int c = 0; c < 20; ++c) o[c] = p[c] + lbias[c];
        }
    }
}

// ---------------- column-wise logsumexp over 36960 rows ----------------
__global__ void __launch_bounds__(256) k_lsepart(const float* __restrict__ logits,
                                                 float2* __restrict__ part) {
    float m[20], sm[20];
    #pragma unroll
    for (int c = 0; c < 20; ++c) { m[c] = -1e30f; sm[c] = 0.f; }
    for (int row = blockIdx.x * 256 + threadIdx.x; row < NSPAN; row += gridDim.x * 256) {
        const float* r = logits + (size_t)row * 20;
        #pragma unroll
        for (int c = 0; c < 20; ++c) {
            float x = r[c];
            float nm = fmaxf(m[c], x);
            sm[c] = sm[c] * expf(m[c] - nm) + expf(x - nm);
            m[c] = nm;
        }
    }
    __shared__ float2 red[256][20];
    #pragma unroll
    for (int c = 0; c < 20; ++c) red[threadIdx.x][c] = make_float2(m[c], sm[c]);
    __syncthreads();
    for (int st = 128; st; st >>= 1) {
        if (threadIdx.x < st) {
            #pragma unroll
            for (int c = 0; c < 20; ++c) {
                float2 a = red[threadIdx.x][c], b = red[threadIdx.x + st][c];
                float nm = fmaxf(a.x, b.x);
                float ss = a.y * expf(a.x - nm) + b.y * expf(b.x - nm);
                red[threadIdx.x][c] = make_float2(nm, ss);
            }
        }
        __syncthreads();
    }
    if (threadIdx.x < 20) part[(size_t)blockIdx.x * 20 + threadIdx.x] = red[0][threadIdx.x];
}

__global__ void k_lsefin(const float2* __restrict__ part, int nparts, float* __restrict__ lse) {
    int c = threadIdx.x;
    if (c >= 20) return;
    float m = -1e30f, s = 0.f;
    for (int i = 0; i < nparts; ++i) {
        float2 a = part[(size_t)i * 20 + c];
        float nm = fmaxf(m, a.x);
        s = s * expf(m - nm) + a.y * expf(a.x - nm);
        m = nm;
    }
    lse[c] = m + logf(s);
}

__global__ void k_sub(float* __restrict__ out, const float* __restrict__ lse) {
    int i = blockIdx.x * 256 + threadIdx.x;
    if (i < NSPAN * 20) out[i] -= lse[i % 20];
}

// ---------------- launch ----------------
extern "C" void kernel_launch(void* const* d_in, const int* in_sizes, int n_in,
                              void* d_out, int out_size, void* d_ws, size_t ws_size,
                              hipStream_t stream) {
    (void)in_sizes; (void)n_in; (void)out_size; (void)ws_size;
    const int*   tokens = (const int*)  d_in[0];
    const float* emb    = (const float*)d_in[1];
    const float* w_ih_f = (const float*)d_in[2];
    const float* w_hh_f = (const float*)d_in[3];
    const float* b_ih_f = (const float*)d_in[4];
    const float* b_hh_f = (const float*)d_in[5];
    const float* w_ih_b = (const float*)d_in[6];
    const float* w_hh_b = (const float*)d_in[7];
    const float* b_ih_b = (const float*)d_in[8];
    const float* b_hh_b = (const float*)d_in[9];
    const float* lin1_w = (const float*)d_in[10];
    const float* lin1_b = (const float*)d_in[11];
    const float* lin2_w = (const float*)d_in[12];
    const float* lin2_b = (const float*)d_in[13];
    const float* ln_g   = (const float*)d_in[14];
    const float* ln_b   = (const float*)d_in[15];
    const float* label_w= (const float*)d_in[16];
    const float* label_b= (const float*)d_in[17];
    float* out = (float*)d_out;

    char* ws = (char*)d_ws;
    size_t off = 0;
    auto alloc = [&](size_t bytes) { char* p = ws + off; off += (bytes + 255) & ~size_t(255); return p; };
    short*  xbf   = (short*)alloc(3840ull * 256 * 2);
    short*  wihbf = (short*)alloc(4096ull * 256 * 2);
    short*  whhbf = (short*)alloc(2ull * 2048 * 512 * 2);
    short*  l1wbf = (short*)alloc(512ull * 1024 * 2);
    short*  l2wbf = (short*)alloc(512ull * 512 * 2);
    float*  biasc = (float*)alloc(4096ull * 4);
    short*  xg    = (short*)alloc(120ull * 4096 * 32 * 2);
    short*  hbuf  = (short*)alloc(4ull * 32 * 512 * 2);
    short*  rnn   = (short*)alloc(3840ull * 1024 * 2);
    short*  h1    = (short*)alloc(3840ull * 512 * 2);
    float*  h2    = (float*)alloc(3840ull * 512 * 4);
    float*  tr    = (float*)alloc(3840ull * 512 * 4);
    float*  cs    = (float*)alloc(32ull * 121 * 512 * 4);
    int*    ctr   = (int*)  alloc(1024);
    float2* part  = (float2*)alloc(120ull * 20 * 8);
    float*  lse   = (float*)alloc(256);

    hipMemsetAsync(hbuf, 0, 4ull * 32 * 512 * 2, stream);
    hipMemsetAsync(ctr, 0, 1024, stream);

    k_gather<<<3840, 256, 0, stream>>>(tokens, emb, xbf);
    int n8;
    n8 = 2048 * 256 / 8; k_convert<<<(n8 + 255) / 256, 256, 0, stream>>>(w_ih_f, wihbf, n8);
    n8 = 2048 * 256 / 8; k_convert<<<(n8 + 255) / 256, 256, 0, stream>>>(w_ih_b, wihbf + 2048ull * 256, n8);
    n8 = 2048 * 512 / 8; k_convert<<<(n8 + 255) / 256, 256, 0, stream>>>(w_hh_f, whhbf, n8);
    n8 = 2048 * 512 / 8; k_convert<<<(n8 + 255) / 256, 256, 0, stream>>>(w_hh_b, whhbf + 2048ull * 512, n8);
    n8 = 512 * 1024 / 8; k_convert<<<(n8 + 255) / 256, 256, 0, stream>>>(lin1_w, l1wbf, n8);
    n8 = 512 * 512 / 8;  k_convert<<<(n8 + 255) / 256, 256, 0, stream>>>(lin2_w, l2wbf, n8);
    k_biascomb<<<16, 256, 0, stream>>>(b_ih_f, b_hh_f, b_ih_b, b_hh_b, biasc);

    // xg[t][g(4096)][b] = x @ [w_ih_f; w_ih_b]^T + (b_ih + b_hh)
    k_gemm<2><<<dim3(60, 64), 256, 0, stream>>>(xbf, wihbf, biasc, nullptr, xg, 4096, 256);
    // recurrence -> rnn[b*T+t][1024] (fwd | bwd)
    k_lstm<<<64, 256, 0, stream>>>(xg, whhbf, hbuf, rnn, ctr);
    // lin1 + relu -> bf16
    k_gemm<1><<<dim3(60, 8), 256, 0, stream>>>(rnn, l1wbf, lin1_b, nullptr, h1, 512, 1024);
    // lin2 -> fp32
    k_gemm<0><<<dim3(60, 8), 256, 0, stream>>>(h1, l2wbf, lin2_b, h2, nullptr, 512, 512);
    k_ln<<<960, 256, 0, stream>>>(h2, ln_g, ln_b, tr);
    k_cumsum<<<32, 512, 0, stream>>>(tr, cs);
    k_span<<<512, 256, 0, stream>>>(cs, label_w, label_b, out);
    k_lsepart<<<120, 256, 0, stream>>>(out, part);
    k_lsefin<<<1, 32, 0, stream>>>(part, 120, lse);
    k_sub<<<(NSPAN * 20 + 255) / 256, 256, 0, stream>>>(out, lse);
}

// Round 2
// 850.228 us; speedup vs baseline: 2.9513x; 2.9513x over previous
//
#include <hip/hip_runtime.h>

#define B_ 32
#define T_ 120
#define E_ 256
#define H_ 512
#define NSPAN 36960   // B_ * 1155

typedef __attribute__((ext_vector_type(8))) short short8;
typedef __attribute__((ext_vector_type(4))) short sshort4;
typedef __attribute__((ext_vector_type(4))) float f32x4;
typedef __attribute__((ext_vector_type(4))) unsigned int u32x4;

__device__ __forceinline__ short f2bf(float x) {
    union { float f; unsigned u; } v; v.f = x;
    unsigned r = v.u + 0x7fffu + ((v.u >> 16) & 1u);
    return (short)(r >> 16);
}
__device__ __forceinline__ float bf2f(unsigned short x) {
    union { unsigned u; float f; } v; v.u = ((unsigned)x) << 16;
    return v.f;
}
__device__ __forceinline__ int load_coh_i32(const int* p) {
    int r;
    asm volatile("global_load_dword %0, %1, off sc0 sc1\n\ts_waitcnt vmcnt(0)"
                 : "=v"(r) : "v"(p) : "memory");
    return r;
}

// ---------------- gather tokens -> x bf16 (row m = t*32 + b) ----------------
__global__ void k_gather(const int* __restrict__ tokens, const float* __restrict__ emb,
                         short* __restrict__ xbf) {
    int m = blockIdx.x;              // 0..3839, m = t*32+b
    int t = m >> 5, b = m & 31;
    int tok = tokens[b * T_ + t];
    int e = threadIdx.x;             // 256
    xbf[(size_t)m * E_ + e] = f2bf(emb[(size_t)tok * E_ + e]);
}

// ---------------- fp32 -> bf16 convert ----------------
__global__ void k_convert(const float* __restrict__ src, short* __restrict__ dst, int n8) {
    int i = blockIdx.x * blockDim.x + threadIdx.x;
    if (i >= n8) return;
    const float4* s4 = (const float4*)src + (size_t)i * 2;
    float4 a = s4[0], b = s4[1];
    short8 o;
    o[0]=f2bf(a.x); o[1]=f2bf(a.y); o[2]=f2bf(a.z); o[3]=f2bf(a.w);
    o[4]=f2bf(b.x); o[5]=f2bf(b.y); o[6]=f2bf(b.z); o[7]=f2bf(b.w);
    *(short8*)(dst + (size_t)i * 8) = o;
}

__global__ void k_biascomb(const float* __restrict__ bf1, const float* __restrict__ bf2,
                           const float* __restrict__ bb1, const float* __restrict__ bb2,
                           float* __restrict__ out) {
    int i = blockIdx.x * 256 + threadIdx.x;   // 4096
    out[i] = (i < 2048) ? (bf1[i] + bf2[i]) : (bb1[i - 2048] + bb2[i - 2048]);
}

// ---------------- generic bf16 MFMA GEMM: out = A(MxK) @ W(NxK)^T + bias ----------------
// EPI 0: fp32 row-major out ; EPI 1: relu -> bf16 row-major ; EPI 2: bf16 scatter to xg[t][n][b]
template <int EPI>
__global__ void __launch_bounds__(256) k_gemm(const short* __restrict__ A,
                                              const short* __restrict__ W,
                                              const float* __restrict__ bias,
                                              float* __restrict__ outF,
                                              short* __restrict__ outB,
                                              int N, int K) {
    int w = threadIdx.x >> 6, l = threadIdx.x & 63;
    int la = l & 15, lb = l >> 4;
    int m0 = blockIdx.x * 64 + w * 16;
    int nb = blockIdx.y * 64;
    const short* Ap = A + (size_t)(m0 + la) * K + lb * 8;
    const short* Wp = W + (size_t)(nb + la) * K + lb * 8;
    f32x4 acc0 = {0.f,0.f,0.f,0.f}, acc1 = acc0, acc2 = acc0, acc3 = acc0;
    for (int k0 = 0; k0 < K; k0 += 32) {
        short8 a  = *(const short8*)(Ap + k0);
        short8 b0 = *(const short8*)(Wp + k0);
        short8 b1 = *(const short8*)(Wp + (size_t)16 * K + k0);
        short8 b2 = *(const short8*)(Wp + (size_t)32 * K + k0);
        short8 b3 = *(const short8*)(Wp + (size_t)48 * K + k0);
        acc0 = __builtin_amdgcn_mfma_f32_16x16x32_bf16(a, b0, acc0, 0, 0, 0);
        acc1 = __builtin_amdgcn_mfma_f32_16x16x32_bf16(a, b1, acc1, 0, 0, 0);
        acc2 = __builtin_amdgcn_mfma_f32_16x16x32_bf16(a, b2, acc2, 0, 0, 0);
        acc3 = __builtin_amdgcn_mfma_f32_16x16x32_bf16(a, b3, acc3, 0, 0, 0);
    }
    f32x4 accs[4] = {acc0, acc1, acc2, acc3};
    #pragma unroll
    for (int j = 0; j < 4; ++j) {
        int n = nb + j * 16 + la;
        float bv = bias[n];
        if (EPI == 2) {
            int mb = m0 + lb * 4;
            int t = mb >> 5, b0i = mb & 31;
            sshort4 pk;
            #pragma unroll
            for (int r = 0; r < 4; ++r) pk[r] = f2bf(accs[j][r] + bv);
            *(sshort4*)(outB + (((size_t)t * 4096 + n) << 5) + b0i) = pk;
        } else {
            #pragma unroll
            for (int r = 0; r < 4; ++r) {
                int m = m0 + lb * 4 + r;
                float v = accs[j][r] + bv;
                if (EPI == 0) outF[(size_t)m * N + n] = v;
                else          outB[(size_t)m * N + n] = f2bf(fmaxf(v, 0.f));
            }
        }
    }
}

// ---------------- persistent bidirectional LSTM ----------------
// 64 blocks: dir = bid>>5, jslice = bid&31 (16 j's each). No agent fences:
// h exchanged via write-through (sc0 sc1) stores to IC + uncached staging loads.
__global__ void __launch_bounds__(256, 1) k_lstm(const short* __restrict__ xg,
                                                 const short* __restrict__ whh,
                                                 short* __restrict__ hbuf,
                                                 short* __restrict__ rnn,
                                                 int* __restrict__ ctr) {
    __shared__ short wlds[4][16][512];   // 64 KiB
    __shared__ short hlds[32][512];      // 32 KiB
    int tid = threadIdx.x;
    int w = tid >> 6, l = tid & 63;
    int la = l & 15, lb = l >> 4;
    int bid = blockIdx.x;
    int dir = bid >> 5, jsl = bid & 31;
    int jw = jsl * 16 + w * 4;

    // stage weights, swizzled: row rr at byte rr*1024, 16B chunk c16 at (c16*16)^((rr&7)<<4)
    {
        char* base = (char*)&wlds[w][0][0];
        for (int cc = l; cc < 1024; cc += 64) {
            int rr = cc >> 6, c16 = cc & 63;
            int gate = rr >> 2, jj = rr & 3;
            short8 v = *(const short8*)(whh + ((size_t)dir * 2048 + gate * 512 + jw + jj) * 512 + c16 * 8);
            *(short8*)(base + rr * 1024 + ((c16 * 16) ^ ((rr & 7) << 4))) = v;
        }
    }
    __syncthreads();

    float cst[2][4] = {{0.f,0.f,0.f,0.f},{0.f,0.f,0.f,0.f}};
    int gate = la >> 2;
    int grow = dir * 2048 + gate * 512 + jw + (la & 3);
    const char* wrow = (const char*)&wlds[w][0][0] + la * 1024;
    const char* hrow0 = (const char*)&hlds[0][0] + la * 1024;
    const char* hrow1 = hrow0 + 16 * 1024;
    int swz = (la & 7) << 4;
    int* ctrd = ctr + dir * T_;

    for (int s = 0; s < T_; ++s) {
        int t = dir ? (T_ - 1 - s) : s;
        int cur = s & 1;
        const short* hb = hbuf + (size_t)(dir * 2 + cur) * (32 * 512);
        short* hn = hbuf + (size_t)(dir * 2 + (1 - cur)) * (32 * 512);

        // wait for all 32 blocks of this dir to publish h_{s-1}
        if (s > 0) {
            if (tid == 0) {
                const int* cp = ctrd + (s - 1);
                while (load_coh_i32(cp) < 32) __builtin_amdgcn_s_sleep(1);
            }
            __syncthreads();
        }

        // stage h (32 KB) into LDS via uncached 16B loads (bypass stale L2)
        unsigned long long x0, x1;
        {
            u32x4 vv[8];
            const char* src = (const char*)hb;
            #pragma unroll
            for (int i = 0; i < 8; ++i)
                asm volatile("global_load_dwordx4 %0, %1, off sc0 sc1"
                             : "=v"(vv[i]) : "v"(src + (tid + 256 * i) * 16));
            // xg for this step (normal cached loads), overlapped
            const short* xgp = xg + ((size_t)t * 4096 + grow) * 32;
            x0 = *(const unsigned long long*)(xgp + lb * 4);
            x1 = *(const unsigned long long*)(xgp + 16 + lb * 4);
            asm volatile("s_waitcnt vmcnt(0)" ::: "memory");
            char* hdst = (char*)&hlds[0][0];
            #pragma unroll
            for (int i = 0; i < 8; ++i) {
                int byte = (tid + 256 * i) << 4;
                int row = byte >> 10, col = byte & 1023;
                *(u32x4*)(hdst + row * 1024 + (col ^ ((row & 7) << 4))) = vv[i];
            }
        }
        __syncthreads();

        float xv[2][4];
        #pragma unroll
        for (int r = 0; r < 4; ++r) {
            xv[0][r] = bf2f((unsigned short)((x0 >> (16 * r)) & 0xffffu));
            xv[1][r] = bf2f((unsigned short)((x1 >> (16 * r)) & 0xffffu));
        }

        f32x4 a0A = {0.f,0.f,0.f,0.f}, a0B = a0A, a1A = a0A, a1B = a0A;
        #pragma unroll
        for (int ks2 = 0; ks2 < 8; ++ks2) {
            int co0 = ((ks2 * 128) + lb * 16) ^ swz;
            int co1 = co0 ^ 64;
            short8 wA = *(const short8*)(wrow + co0);
            short8 wB = *(const short8*)(wrow + co1);
            short8 h0A = *(const short8*)(hrow0 + co0);
            short8 h0B = *(const short8*)(hrow0 + co1);
            short8 h1A = *(const short8*)(hrow1 + co0);
            short8 h1B = *(const short8*)(hrow1 + co1);
            a0A = __builtin_amdgcn_mfma_f32_16x16x32_bf16(h0A, wA, a0A, 0, 0, 0);
            a1A = __builtin_amdgcn_mfma_f32_16x16x32_bf16(h1A, wA, a1A, 0, 0, 0);
            a0B = __builtin_amdgcn_mfma_f32_16x16x32_bf16(h0B, wB, a0B, 0, 0, 0);
            a1B = __builtin_amdgcn_mfma_f32_16x16x32_bf16(h1B, wB, a1B, 0, 0, 0);
        }
        f32x4 a0 = a0A + a0B, a1 = a1A + a1B;

        float val[2][4];
        #pragma unroll
        for (int mt = 0; mt < 2; ++mt) {
            #pragma unroll
            for (int r = 0; r < 4; ++r) {
                float x = (mt ? a1[r] : a0[r]) + xv[mt][r];
                // gate==2 -> tanh, else sigmoid (fast exp2-based)
                val[mt][r] = (gate == 2) ? (1.f - 2.f / (1.f + __expf(2.f * x)))
                                         : (1.f / (1.f + __expf(-x)));
            }
        }

        #pragma unroll
        for (int mt = 0; mt < 2; ++mt) {
            #pragma unroll
            for (int r = 0; r < 4; ++r) {
                float v = val[mt][r];
                float vf = __shfl_xor(v, 4);
                float vg = __shfl_xor(v, 8);
                float vo = __shfl_xor(v, 12);
                if (la < 4) {   // gate==0 lanes: v=sig(i), vf=sig(f), vg=tanh(g), vo=sig(o)
                    float c = vf * cst[mt][r] + v * vg;
                    cst[mt][r] = c;
                    float h = vo * (1.f - 2.f / (1.f + __expf(2.f * c)));
                    short hv = f2bf(h);
                    int hvi = (unsigned short)hv;
                    int b = mt * 16 + lb * 4 + r;
                    asm volatile("global_store_short %0, %1, off sc0 sc1"
                                 :: "v"(hn + (size_t)b * 512 + jw + la), "v"(hvi) : "memory");
                    rnn[((size_t)b * T_ + t) * 1024 + dir * 512 + jw + la] = hv;
                }
            }
        }

        asm volatile("s_waitcnt vmcnt(0)" ::: "memory");   // h stores ack'd at IC
        __syncthreads();                                   // whole block done
        if (tid == 0)
            __hip_atomic_fetch_add(ctrd + s, 1, __ATOMIC_RELAXED, __HIP_MEMORY_SCOPE_AGENT);
    }
}

// ---------------- LayerNorm (wave per row of 512) ----------------
__global__ void k_ln(const float* __restrict__ h2, const float* __restrict__ gam,
                     const float* __restrict__ bet, float* __restrict__ tr) {
    int w = threadIdx.x >> 6, l = threadIdx.x & 63;
    size_t row = (size_t)blockIdx.x * 4 + w;
    const float* x = h2 + row * 512;
    float v[8], s = 0.f, s2 = 0.f;
    #pragma unroll
    for (int i = 0; i < 8; ++i) { v[i] = x[l + 64 * i]; s += v[i]; s2 += v[i] * v[i]; }
    #pragma unroll
    for (int off = 32; off; off >>= 1) { s += __shfl_xor(s, off); s2 += __shfl_xor(s2, off); }
    float mu = s * (1.f / 512.f);
    float var = s2 * (1.f / 512.f) - mu * mu;
    float rstd = 1.f / sqrtf(var + 1e-5f);
    float* o = tr + row * 512;
    #pragma unroll
    for (int i = 0; i < 8; ++i) { int k = l + 64 * i; o[k] = (v[i] - mu) * rstd * gam[k] + bet[k]; }
}

// ---------------- cumsum over t (block per batch, thread per feature) ----------------
__global__ void k_cumsum(const float* __restrict__ tr, float* __restrict__ cs) {
    int b = blockIdx.x, f = threadIdx.x;  // 512 threads
    cs[((size_t)b * 121) * 512 + f] = 0.f;
    const float* src = tr + ((size_t)b * 120) * 512 + f;
    float* dst = cs + ((size_t)b * 121 + 1) * 512 + f;
    float run = 0.f;
    float nxt = src[0];
    for (int t = 0; t < 120; ++t) {
        float c = nxt;
        if (t < 119) nxt = src[(size_t)(t + 1) * 512];
        run += c;
        dst[(size_t)t * 512] = run;
    }
}

// ---------------- spans + label GEMM (wave per span) ----------------
__global__ void __launch_bounds__(256) k_span(const float* __restrict__ cs,
                                              const float* __restrict__ lw,
                                              const float* __restrict__ lbias,
                                              float* __restrict__ out) {
    __shared__ float wl[20][512];
    for (int idx = threadIdx.x; idx < 20 * 512; idx += 256) {
        int c = idx >> 9, k = idx & 511;
        wl[c][k] = lw[(size_t)k * 20 + c];
    }
    __syncthreads();
    int w = threadIdx.x >> 6, l = threadIdx.x & 63;
    int nw = gridDim.x * 4;
    for (int sp = blockIdx.x * 4 + w; sp < NSPAN; sp += nw) {
        int b = sp / 1155, s = sp - b * 1155;
        int beg, len;
        if (s < 1110) { beg = s / 10; len = s - beg * 10 + 1; }
        else {
            int t2 = s - 1110; beg = 111; int ll = 9;
            while (t2 >= ll) { t2 -= ll; --ll; ++beg; }
            len = t2 + 1;
        }
        int end = beg + len;
        const float* ce = cs + ((size_t)b * 121 + end) * 512;
        const float* cb = cs + ((size_t)b * 121 + beg) * 512;
        float inv = 1.f / (float)len;
        float p[20];
        #pragma unroll
        for (int c = 0; c < 20; ++c) p[c] = 0.f;
        #pragma unroll
        for (int i = 0; i < 8; ++i) {
            int k = l + 64 * i;
            float d = (ce[k] - cb[k]) * inv;
            #pragma unroll
            for (int c = 0; c < 20; ++c) p[c] += d * wl[c][k];
        }
        #pragma unroll
        for (int off = 32; off; off >>= 1) {
            #pragma unroll
            for (int c = 0; c < 20; ++c) p[c] += __shfl_xor(p[c], off);
        }
        if (l == 0) {
            float* o = out + (size_t)sp * 20;
            #pragma unroll
            for (int c = 0; c < 20; ++c) o[c] = p[c] + lbias[c];
        }
    }
}

// ---------------- column-wise logsumexp over 36960 rows ----------------
__global__ void __launch_bounds__(256) k_lsepart(const float* __restrict__ logits,
                                                 float2* __restrict__ part) {
    float m[20], sm[20];
    #pragma unroll
    for (int c = 0; c < 20; ++c) { m[c] = -1e30f; sm[c] = 0.f; }
    for (int row = blockIdx.x * 256 + threadIdx.x; row < NSPAN; row += gridDim.x * 256) {
        const float* r = logits + (size_t)row * 20;
        #pragma unroll
        for (int c = 0; c < 20; ++c) {
            float x = r[c];
            float nm = fmaxf(m[c], x);
            sm[c] = sm[c] * expf(m[c] - nm) + expf(x - nm);
            m[c] = nm;
        }
    }
    __shared__ float2 red[256][20];
    #pragma unroll
    for (int c = 0; c < 20; ++c) red[threadIdx.x][c] = make_float2(m[c], sm[c]);
    __syncthreads();
    for (int st = 128; st; st >>= 1) {
        if (threadIdx.x < st) {
            #pragma unroll
            for (int c = 0; c < 20; ++c) {
                float2 a = red[threadIdx.x][c], b = red[threadIdx.x + st][c];
                float nm = fmaxf(a.x, b.x);
                float ss = a.y * expf(a.x - nm) + b.y * expf(b.x - nm);
                red[threadIdx.x][c] = make_float2(nm, ss);
            }
        }
        __syncthreads();
    }
    if (threadIdx.x < 20) part[(size_t)blockIdx.x * 20 + threadIdx.x] = red[0][threadIdx.x];
}

__global__ void k_lsefin(const float2* __restrict__ part, int nparts, float* __restrict__ lse) {
    int c = threadIdx.x;
    if (c >= 20) return;
    float m = -1e30f, s = 0.f;
    for (int i = 0; i < nparts; ++i) {
        float2 a = part[(size_t)i * 20 + c];
        float nm = fmaxf(m, a.x);
        s = s * expf(m - nm) + a.y * expf(a.x - nm);
        m = nm;
    }
    lse[c] = m + logf(s);
}

__global__ void k_sub(float* __restrict__ out, const float* __restrict__ lse) {
    int i = blockIdx.x * 256 + threadIdx.x;
    if (i < NSPAN * 20) out[i] -= lse[i % 20];
}

// ---------------- launch ----------------
extern "C" void kernel_launch(void* const* d_in, const int* in_sizes, int n_in,
                              void* d_out, int out_size, void* d_ws, size_t ws_size,
                              hipStream_t stream) {
    (void)in_sizes; (void)n_in; (void)out_size; (void)ws_size;
    const int*   tokens = (const int*)  d_in[0];
    const float* emb    = (const float*)d_in[1];
    const float* w_ih_f = (const float*)d_in[2];
    const float* w_hh_f = (const float*)d_in[3];
    const float* b_ih_f = (const float*)d_in[4];
    const float* b_hh_f = (const float*)d_in[5];
    const float* w_ih_b = (const float*)d_in[6];
    const float* w_hh_b = (const float*)d_in[7];
    const float* b_ih_b = (const float*)d_in[8];
    const float* b_hh_b = (const float*)d_in[9];
    const float* lin1_w = (const float*)d_in[10];
    const float* lin1_b = (const float*)d_in[11];
    const float* lin2_w = (const float*)d_in[12];
    const float* lin2_b = (const float*)d_in[13];
    const float* ln_g   = (const float*)d_in[14];
    const float* ln_b   = (const float*)d_in[15];
    const float* label_w= (const float*)d_in[16];
    const float* label_b= (const float*)d_in[17];
    float* out = (float*)d_out;

    char* ws = (char*)d_ws;
    size_t off = 0;
    auto alloc = [&](size_t bytes) { char* p = ws + off; off += (bytes + 255) & ~size_t(255); return p; };
    short*  xbf   = (short*)alloc(3840ull * 256 * 2);
    short*  wihbf = (short*)alloc(4096ull * 256 * 2);
    short*  whhbf = (short*)alloc(2ull * 2048 * 512 * 2);
    short*  l1wbf = (short*)alloc(512ull * 1024 * 2);
    short*  l2wbf = (short*)alloc(512ull * 512 * 2);
    float*  biasc = (float*)alloc(4096ull * 4);
    short*  xg    = (short*)alloc(120ull * 4096 * 32 * 2);
    short*  hbuf  = (short*)alloc(4ull * 32 * 512 * 2);
    short*  rnn   = (short*)alloc(3840ull * 1024 * 2);
    short*  h1    = (short*)alloc(3840ull * 512 * 2);
    float*  h2    = (float*)alloc(3840ull * 512 * 4);
    float*  tr    = (float*)alloc(3840ull * 512 * 4);
    float*  cs    = (float*)alloc(32ull * 121 * 512 * 4);
    int*    ctr   = (int*)  alloc(1024);
    float2* part  = (float2*)alloc(120ull * 20 * 8);
    float*  lse   = (float*)alloc(256);

    hipMemsetAsync(hbuf, 0, 4ull * 32 * 512 * 2, stream);
    hipMemsetAsync(ctr, 0, 1024, stream);

    k_gather<<<3840, 256, 0, stream>>>(tokens, emb, xbf);
    int n8;
    n8 = 2048 * 256 / 8; k_convert<<<(n8 + 255) / 256, 256, 0, stream>>>(w_ih_f, wihbf, n8);
    n8 = 2048 * 256 / 8; k_convert<<<(n8 + 255) / 256, 256, 0, stream>>>(w_ih_b, wihbf + 2048ull * 256, n8);
    n8 = 2048 * 512 / 8; k_convert<<<(n8 + 255) / 256, 256, 0, stream>>>(w_hh_f, whhbf, n8);
    n8 = 2048 * 512 / 8; k_convert<<<(n8 + 255) / 256, 256, 0, stream>>>(w_hh_b, whhbf + 2048ull * 512, n8);
    n8 = 512 * 1024 / 8; k_convert<<<(n8 + 255) / 256, 256, 0, stream>>>(lin1_w, l1wbf, n8);
    n8 = 512 * 512 / 8;  k_convert<<<(n8 + 255) / 256, 256, 0, stream>>>(lin2_w, l2wbf, n8);
    k_biascomb<<<16, 256, 0, stream>>>(b_ih_f, b_hh_f, b_ih_b, b_hh_b, biasc);

    // xg[t][g(4096)][b] = x @ [w_ih_f; w_ih_b]^T + (b_ih + b_hh)
    k_gemm<2><<<dim3(60, 64), 256, 0, stream>>>(xbf, wihbf, biasc, nullptr, xg, 4096, 256);
    // recurrence -> rnn[b*T+t][1024] (fwd | bwd)
    k_lstm<<<64, 256, 0, stream>>>(xg, whhbf, hbuf, rnn, ctr);
    // lin1 + relu -> bf16
    k_gemm<1><<<dim3(60, 8), 256, 0, stream>>>(rnn, l1wbf, lin1_b, nullptr, h1, 512, 1024);
    // lin2 -> fp32
    k_gemm<0><<<dim3(60, 8), 256, 0, stream>>>(h1, l2wbf, lin2_b, h2, nullptr, 512, 512);
    k_ln<<<960, 256, 0, stream>>>(h2, ln_g, ln_b, tr);
    k_cumsum<<<32, 512, 0, stream>>>(tr, cs);
    k_span<<<512, 256, 0, stream>>>(cs, label_w, label_b, out);
    k_lsepart<<<120, 256, 0, stream>>>(out, part);
    k_lsefin<<<1, 32, 0, stream>>>(part, 120, lse);
    k_sub<<<(NSPAN * 20 + 255) / 256, 256, 0, stream>>>(out, lse);
}